// Round 1
// baseline (67.508 us; speedup 1.0000x reference)
//
#include <hip/hip_runtime.h>
#include <hip/hip_bf16.h>

#define BB 2
#define NN 512
#define FIN 128
#define HH 4
#define DD 64
#define NEG 0.2f

// ---------------------------------------------------------------------------
// Kernel A: h = x @ W_proj + b_proj ; zi = h @ W1^T + W_cat_bias ; zj = h @ W2^T
// grid = B*H*(N/16) = 256 blocks, 256 threads
// ---------------------------------------------------------------------------
__global__ __launch_bounds__(256) void proj_kernel(
    const float* __restrict__ x, const float* __restrict__ Wp,
    const float* __restrict__ bp, const float* __restrict__ Wc,
    const float* __restrict__ Wcb,
    float* __restrict__ h_ws, float* __restrict__ zi_ws, float* __restrict__ zj_ws)
{
    int blk = blockIdx.x;
    int bh = blk >> 5;             // / 32 tiles per (b,h)
    int n0 = (blk & 31) << 4;      // * 16
    int b  = bh >> 2;
    int hh = bh & 3;

    __shared__ float xs[16 * FIN];   // 8 KB, reads are wave-uniform (broadcast)
    __shared__ float hs[16][DD];     // 4 KB, reads are wave-uniform (broadcast)

    int t = threadIdx.x;

    // load x tile: 16 rows x 128 = 2048 floats = 512 float4
    {
        const float4* xg = (const float4*)(x + ((size_t)b * NN + n0) * FIN);
        float4* xs4 = (float4*)xs;
        xs4[t]       = xg[t];
        xs4[t + 256] = xg[t + 256];
    }
    __syncthreads();

    int d = t & 63;
    int w = t >> 6;                 // wave id: handles rows w, w+4, w+8, w+12
    const float* Wph = Wp + (size_t)hh * FIN * DD;

    float acc[4];
    float bpv = bp[hh * DD + d];
    #pragma unroll
    for (int k = 0; k < 4; ++k) acc[k] = bpv;

    for (int i = 0; i < FIN; ++i) {
        float wv = Wph[i * DD + d];           // coalesced, L1-resident
        #pragma unroll
        for (int k = 0; k < 4; ++k)
            acc[k] = fmaf(xs[(w + 4 * k) * FIN + i], wv, acc[k]);
    }

    float* hrow_g = h_ws + ((size_t)bh * NN + n0) * DD;
    #pragma unroll
    for (int k = 0; k < 4; ++k) {
        int r = w + 4 * k;
        hs[r][d] = acc[k];
        hrow_g[r * DD + d] = acc[k];
    }
    __syncthreads();

    // zi/zj: zi[n,e] = sum_d hs[n,d] * Wc[h,e,d] (+Wcb), zj uses Wc[h,e,D+d]
    int e = d;
    const float* Wch = Wc + (size_t)hh * DD * 2 * DD;
    float zi_acc[4], zj_acc[4];
    float zb = Wcb[hh * DD + e];
    #pragma unroll
    for (int k = 0; k < 4; ++k) { zi_acc[k] = zb; zj_acc[k] = 0.f; }

    for (int d2 = 0; d2 < DD; ++d2) {
        float w1 = Wch[e * 2 * DD + d2];
        float w2 = Wch[e * 2 * DD + DD + d2];
        #pragma unroll
        for (int k = 0; k < 4; ++k) {
            float hv = hs[w + 4 * k][d2];     // broadcast
            zi_acc[k] = fmaf(hv, w1, zi_acc[k]);
            zj_acc[k] = fmaf(hv, w2, zj_acc[k]);
        }
    }

    float* zib = zi_ws + ((size_t)bh * NN + n0) * DD;
    float* zjb = zj_ws + ((size_t)bh * NN + n0) * DD;
    #pragma unroll
    for (int k = 0; k < 4; ++k) {
        zib[(w + 4 * k) * DD + e] = zi_acc[k];
        zjb[(w + 4 * k) * DD + e] = zj_acc[k];
    }
}

// ---------------------------------------------------------------------------
// Kernel B: attention. grid = B*H*(N/8) = 512 blocks, 256 threads.
// Ti = 8 query rows per block; zj/h streamed in 64-row LDS tiles.
// ---------------------------------------------------------------------------
__global__ __launch_bounds__(256) void attn_kernel(
    const float* __restrict__ h_ws, const float* __restrict__ zi_ws,
    const float* __restrict__ zj_ws, const float* __restrict__ a,
    const float* __restrict__ bias_param, float* __restrict__ out)
{
    int blk = blockIdx.x;
    int bh = blk >> 6;             // 64 i-tiles per (b,h)
    int i0 = (blk & 63) << 3;      // * 8
    int b  = bh >> 2;
    int hh = bh & 3;

    __shared__ float zis[8][DD];       // 2 KB
    __shared__ float as[DD];
    __shared__ float tile[64][65];     // 16.25 KB, pad-65 -> 2-way (free)
    __shared__ float es[8][NN];        // 16 KB
    __shared__ float denom[8];

    int t = threadIdx.x;

    {
        const float* zib = zi_ws + ((size_t)bh * NN + i0) * DD;
        zis[(t) >> 6][t & 63]         = zib[t];
        zis[(t + 256) >> 6][t & 63]   = zib[t + 256];
        if (t < DD) as[t] = a[hh * DD + t];
    }

    const float* zjb = zj_ws + (size_t)bh * NN * DD;
    int jl = t & 63;
    int iw = t >> 6;               // this thread covers i-rows iw and iw+4

    // ---- Pass A: scores ----
    for (int jt = 0; jt < 8; ++jt) {
        __syncthreads();           // protects tile from previous use (also zis load @ jt=0)
        const float4* src = (const float4*)(zjb + (size_t)jt * 64 * DD);
        #pragma unroll
        for (int k = 0; k < 4; ++k) {
            int idx = t + 256 * k;         // float4 index into 64x64 tile
            int r = idx >> 4, c4 = (idx & 15) * 4;
            float4 v = src[idx];
            tile[r][c4 + 0] = v.x; tile[r][c4 + 1] = v.y;
            tile[r][c4 + 2] = v.z; tile[r][c4 + 3] = v.w;
        }
        __syncthreads();

        float e0 = 0.f, e1 = 0.f;
        #pragma unroll
        for (int e = 0; e < DD; ++e) {
            float zjv = tile[jl][e];       // 2-way bank alias (free)
            float av  = as[e];             // broadcast
            float z0  = zis[iw][e] + zjv;  // broadcast
            float z1  = zis[iw + 4][e] + zjv;
            z0 = (z0 >= 0.f) ? z0 : NEG * z0;
            z1 = (z1 >= 0.f) ? z1 : NEG * z1;
            e0 = fmaf(av, z0, e0);
            e1 = fmaf(av, z1, e1);
        }
        es[iw][jt * 64 + jl]     = e0;
        es[iw + 4][jt * 64 + jl] = e1;
    }
    __syncthreads();

    // ---- Pass B: softmax over each of the 8 rows (32 lanes per row) ----
    {
        int r = t >> 5, l = t & 31;
        float m = -1e30f;
        #pragma unroll
        for (int k = 0; k < 16; ++k) m = fmaxf(m, es[r][l + 32 * k]);
        #pragma unroll
        for (int off = 16; off; off >>= 1) m = fmaxf(m, __shfl_xor(m, off));
        float s = 0.f;
        #pragma unroll
        for (int k = 0; k < 16; ++k) {
            float p = __expf(es[r][l + 32 * k] - m);
            es[r][l + 32 * k] = p;
            s += p;
        }
        #pragma unroll
        for (int off = 16; off; off >>= 1) s += __shfl_xor(s, off);
        if (l == 0) denom[r] = s;
    }
    __syncthreads();

    // ---- Pass C: PV ----
    const float* hb = h_ws + (size_t)bh * NN * DD;
    float acc0 = 0.f, acc1 = 0.f;
    int dd = t & 63;
    for (int jt = 0; jt < 8; ++jt) {
        __syncthreads();           // protect tile vs previous iteration reads
        const float4* src = (const float4*)(hb + (size_t)jt * 64 * DD);
        #pragma unroll
        for (int k = 0; k < 4; ++k) {
            int idx = t + 256 * k;
            int r = idx >> 4, c4 = (idx & 15) * 4;
            float4 v = src[idx];
            tile[r][c4 + 0] = v.x; tile[r][c4 + 1] = v.y;
            tile[r][c4 + 2] = v.z; tile[r][c4 + 3] = v.w;
        }
        __syncthreads();

        #pragma unroll
        for (int j = 0; j < 64; ++j) {
            float hv = tile[j][dd];        // consecutive -> conflict-free
            acc0 = fmaf(es[iw][jt * 64 + j], hv, acc0);      // es broadcast
            acc1 = fmaf(es[iw + 4][jt * 64 + j], hv, acc1);
        }
    }

    // ---- epilogue ----
    float bpv  = bias_param[hh * DD + dd];
    float inv0 = 1.f / denom[iw];
    float inv1 = 1.f / denom[iw + 4];
    out[((size_t)b * NN + i0 + iw) * (HH * DD) + hh * DD + dd]     = acc0 * inv0 + bpv;
    out[((size_t)b * NN + i0 + iw + 4) * (HH * DD) + hh * DD + dd] = acc1 * inv1 + bpv;
}

extern "C" void kernel_launch(void* const* d_in, const int* in_sizes, int n_in,
                              void* d_out, int out_size, void* d_ws, size_t ws_size,
                              hipStream_t stream) {
    const float* x   = (const float*)d_in[0];
    const float* Wp  = (const float*)d_in[1];
    const float* bp  = (const float*)d_in[2];
    const float* Wc  = (const float*)d_in[3];
    const float* Wcb = (const float*)d_in[4];
    const float* a   = (const float*)d_in[5];
    const float* bpar= (const float*)d_in[6];
    float* out = (float*)d_out;

    float* ws   = (float*)d_ws;
    float* h_ws  = ws;                         // B*H*N*D = 262144 floats
    float* zi_ws = ws + 262144;
    float* zj_ws = ws + 2 * 262144;

    proj_kernel<<<dim3(BB * HH * (NN / 16)), dim3(256), 0, stream>>>(
        x, Wp, bp, Wc, Wcb, h_ws, zi_ws, zj_ws);
    attn_kernel<<<dim3(BB * HH * (NN / 8)), dim3(256), 0, stream>>>(
        h_ws, zi_ws, zj_ws, a, bpar, out);
}

// Round 2
// 46.815 us; speedup vs baseline: 1.4420x; 1.4420x over previous
//
#include <hip/hip_runtime.h>
#include <hip/hip_bf16.h>

#define BB 2
#define NN 512
#define FIN 128
#define HH 4
#define DD 64
// lrelu(z) = 0.6*z + 0.4*|z|  (slope 0.2)

// ws layout (floats):
//  h_ws   [8][512][64]     262144   @ 0
//  zi_ws  [8][512][64]     262144   @ 262144   (includes W_cat_bias)
//  zj_ws  [8][512][64]     262144   @ 524288
//  adi_ws [8][512]         4096     @ 786432   (0.6 * sum_e a*zi)
//  adj_ws [8][512]         4096     @ 790528
//  pacc   [2][8][512][64]  524288   @ 794624
//  pm     [2][8][512]      8192     @ 1318912
//  ps     [2][8][512]      8192     @ 1327104
// total 1335296 floats = 5.34 MB

// ---------------------------------------------------------------------------
// proj: h = x@Wp + bp ; zi = h@W1^T + Wcb ; zj = h@W2^T ; adi/adj dots
// grid = B*H*(N/8) = 512 blocks x 256 thr
// ---------------------------------------------------------------------------
__global__ __launch_bounds__(256) void proj_kernel(
    const float* __restrict__ x, const float* __restrict__ Wp,
    const float* __restrict__ bp, const float* __restrict__ Wc,
    const float* __restrict__ Wcb, const float* __restrict__ a,
    float* __restrict__ h_ws, float* __restrict__ zi_ws, float* __restrict__ zj_ws,
    float* __restrict__ adi_ws, float* __restrict__ adj_ws)
{
    int blk = blockIdx.x;
    int bh = blk >> 6;
    int n0 = (blk & 63) << 3;
    int b = bh >> 2, hh = bh & 3;

    __shared__ float xs[8 * FIN];          // 4 KB
    __shared__ float hs[8][DD];            // 2 KB
    __shared__ float Wcs[DD][2 * DD + 1];  // 64x129 = 33 KB, (e+d2)%32 banks -> free

    int t = threadIdx.x;

    ((float4*)xs)[t] = ((const float4*)(x + ((size_t)b * NN + n0) * FIN))[t];
    {
        const float4* wg = (const float4*)(Wc + (size_t)hh * DD * 2 * DD);
        #pragma unroll
        for (int k = 0; k < 8; ++k) {
            int idx = t + 256 * k;               // 2048 float4 = 64x128
            int r = idx >> 5, c4 = (idx & 31) * 4;
            float4 v = wg[idx];
            Wcs[r][c4] = v.x; Wcs[r][c4 + 1] = v.y;
            Wcs[r][c4 + 2] = v.z; Wcs[r][c4 + 3] = v.w;
        }
    }
    __syncthreads();

    int d = t & 63, w = t >> 6;            // rows w, w+4
    const float* Wph = Wp + (size_t)hh * FIN * DD;
    float bpv = bp[hh * DD + d];
    float acc0 = bpv, acc1 = bpv;
    #pragma unroll 8
    for (int i = 0; i < FIN; ++i) {
        float wv = Wph[i * DD + d];        // coalesced, L1-hot
        acc0 = fmaf(xs[w * FIN + i], wv, acc0);
        acc1 = fmaf(xs[(w + 4) * FIN + i], wv, acc1);
    }
    hs[w][d] = acc0; hs[w + 4][d] = acc1;
    float* hg = h_ws + ((size_t)bh * NN + n0) * DD;
    hg[w * DD + d] = acc0; hg[(w + 4) * DD + d] = acc1;
    __syncthreads();

    int e = d;
    float zb = Wcb[hh * DD + e];
    float zi0 = zb, zi1 = zb, zj0 = 0.f, zj1 = 0.f;
    #pragma unroll 8
    for (int d2 = 0; d2 < DD; ++d2) {
        float w1 = Wcs[e][d2];
        float w2 = Wcs[e][DD + d2];
        float h0 = hs[w][d2], h1 = hs[w + 4][d2];   // broadcast
        zi0 = fmaf(h0, w1, zi0); zi1 = fmaf(h1, w1, zi1);
        zj0 = fmaf(h0, w2, zj0); zj1 = fmaf(h1, w2, zj1);
    }
    float* zib = zi_ws + ((size_t)bh * NN + n0) * DD;
    float* zjb = zj_ws + ((size_t)bh * NN + n0) * DD;
    zib[w * DD + e] = zi0; zib[(w + 4) * DD + e] = zi1;
    zjb[w * DD + e] = zj0; zjb[(w + 4) * DD + e] = zj1;

    // adi = 0.6*sum_e a*zi ; adj = 0.6*sum_e a*zj  (reduce across 64 lanes)
    float av = a[hh * DD + e];
    float p0 = av * zi0, p1 = av * zi1, q0 = av * zj0, q1 = av * zj1;
    #pragma unroll
    for (int off = 32; off; off >>= 1) {
        p0 += __shfl_xor(p0, off); p1 += __shfl_xor(p1, off);
        q0 += __shfl_xor(q0, off); q1 += __shfl_xor(q1, off);
    }
    if (e == 0) {
        adi_ws[bh * NN + n0 + w]     = 0.6f * p0;
        adi_ws[bh * NN + n0 + w + 4] = 0.6f * p1;
        adj_ws[bh * NN + n0 + w]     = 0.6f * q0;
        adj_ws[bh * NN + n0 + w + 4] = 0.6f * q1;
    }
}

// ---------------------------------------------------------------------------
// attn partial: Ti=8 rows, Tj=256 (j-split of 2). grid = 8*64*2 = 1024 blocks.
// ---------------------------------------------------------------------------
__global__ __launch_bounds__(256) void attn_kernel(
    const float* __restrict__ h_ws, const float* __restrict__ zi_ws,
    const float* __restrict__ zj_ws, const float* __restrict__ a,
    const float* __restrict__ adi_ws, const float* __restrict__ adj_ws,
    float* __restrict__ pacc, float* __restrict__ pm, float* __restrict__ ps)
{
    int blk = blockIdx.x;
    int js = blk & 1;
    int it = (blk >> 1) & 63;
    int bh = blk >> 7;
    int i0 = it << 3;
    int hh = bh & 3;

    __shared__ float zis[8][DD];       // 2 KB (reads broadcast)
    __shared__ float as[DD];           // 0.4*a
    __shared__ float adis[8];
    __shared__ float tile[64][65];     // 16.6 KB
    __shared__ float es[8][256];       // 8 KB
    __shared__ float pms[8], pss[8];

    int t = threadIdx.x;
    int jl = t & 63, g = t >> 6;
    int r0 = 2 * g, r1 = 2 * g + 1;

    if (t < 128) ((float4*)zis)[t] =
        ((const float4*)(zi_ws + ((size_t)bh * NN + i0) * DD))[t];
    if (t < DD) as[t] = 0.4f * a[hh * DD + t];
    if (t < 8)  adis[t] = adi_ws[bh * NN + i0 + t];

    const float* zjb  = zj_ws + ((size_t)bh * NN + js * 256) * DD;
    const float* hb   = h_ws  + ((size_t)bh * NN + js * 256) * DD;
    const float* adjb = adj_ws + bh * NN + js * 256;

    // ---- Pass A: scores ----
    for (int jt = 0; jt < 4; ++jt) {
        __syncthreads();
        const float4* src = (const float4*)(zjb + (size_t)jt * 64 * DD);
        #pragma unroll
        for (int k = 0; k < 4; ++k) {
            int idx = t + 256 * k, r = idx >> 4, c4 = (idx & 15) * 4;
            float4 v = src[idx];
            tile[r][c4] = v.x; tile[r][c4 + 1] = v.y;
            tile[r][c4 + 2] = v.z; tile[r][c4 + 3] = v.w;
        }
        float adjv = adjb[jt * 64 + jl];
        __syncthreads();

        float acc0 = 0.f, acc1 = 0.f;
        const float4* z0p = (const float4*)zis[r0];   // broadcast b128
        const float4* z1p = (const float4*)zis[r1];
        const float4* a4p = (const float4*)as;
        const float*  trow = tile[jl];                // 2-way alias -> free
        #pragma unroll
        for (int e4 = 0; e4 < 16; ++e4) {
            float4 za = z0p[e4], zb4 = z1p[e4], av = a4p[e4];
            float t0 = trow[4 * e4 + 0];
            float t1 = trow[4 * e4 + 1];
            float t2 = trow[4 * e4 + 2];
            float t3 = trow[4 * e4 + 3];
            acc0 = fmaf(av.x, __builtin_fabsf(za.x + t0), acc0);
            acc0 = fmaf(av.y, __builtin_fabsf(za.y + t1), acc0);
            acc0 = fmaf(av.z, __builtin_fabsf(za.z + t2), acc0);
            acc0 = fmaf(av.w, __builtin_fabsf(za.w + t3), acc0);
            acc1 = fmaf(av.x, __builtin_fabsf(zb4.x + t0), acc1);
            acc1 = fmaf(av.y, __builtin_fabsf(zb4.y + t1), acc1);
            acc1 = fmaf(av.z, __builtin_fabsf(zb4.z + t2), acc1);
            acc1 = fmaf(av.w, __builtin_fabsf(zb4.w + t3), acc1);
        }
        es[r0][jt * 64 + jl] = adis[r0] + adjv + acc0;
        es[r1][jt * 64 + jl] = adis[r1] + adjv + acc1;
    }
    __syncthreads();

    // ---- partial softmax (8 rows x 32 lanes) ----
    {
        int r = t >> 5, l = t & 31;
        float m = -1e30f;
        #pragma unroll
        for (int k = 0; k < 8; ++k) m = fmaxf(m, es[r][l + 32 * k]);
        #pragma unroll
        for (int off = 16; off; off >>= 1) m = fmaxf(m, __shfl_xor(m, off));
        float s = 0.f;
        #pragma unroll
        for (int k = 0; k < 8; ++k) {
            float p = __expf(es[r][l + 32 * k] - m);
            es[r][l + 32 * k] = p;
            s += p;
        }
        #pragma unroll
        for (int off = 16; off; off >>= 1) s += __shfl_xor(s, off);
        if (l == 0) { pms[r] = m; pss[r] = s; }
    }

    // ---- Pass C: PV (unnormalized) ----
    float acc0 = 0.f, acc1 = 0.f;
    for (int jt = 0; jt < 4; ++jt) {
        __syncthreads();
        const float4* src = (const float4*)(hb + (size_t)jt * 64 * DD);
        #pragma unroll
        for (int k = 0; k < 4; ++k) {
            int idx = t + 256 * k, r = idx >> 4, c4 = (idx & 15) * 4;
            float4 v = src[idx];
            tile[r][c4] = v.x; tile[r][c4 + 1] = v.y;
            tile[r][c4 + 2] = v.z; tile[r][c4 + 3] = v.w;
        }
        __syncthreads();
        const float4* e0p = (const float4*)&es[r0][jt * 64];  // broadcast b128
        const float4* e1p = (const float4*)&es[r1][jt * 64];
        #pragma unroll
        for (int j4 = 0; j4 < 16; ++j4) {
            float4 p0 = e0p[j4], p1 = e1p[j4];
            float h0 = tile[4 * j4 + 0][jl];
            float h1 = tile[4 * j4 + 1][jl];
            float h2 = tile[4 * j4 + 2][jl];
            float h3 = tile[4 * j4 + 3][jl];
            acc0 = fmaf(p0.x, h0, acc0); acc1 = fmaf(p1.x, h0, acc1);
            acc0 = fmaf(p0.y, h1, acc0); acc1 = fmaf(p1.y, h1, acc1);
            acc0 = fmaf(p0.z, h2, acc0); acc1 = fmaf(p1.z, h2, acc1);
            acc0 = fmaf(p0.w, h3, acc0); acc1 = fmaf(p1.w, h3, acc1);
        }
    }

    size_t rowbase = ((size_t)js * 8 + bh) * NN;
    pacc[(rowbase + i0 + r0) * DD + jl] = acc0;
    pacc[(rowbase + i0 + r1) * DD + jl] = acc1;
    if (t < 8) {
        pm[js * 4096 + bh * NN + i0 + t] = pms[t];
        ps[js * 4096 + bh * NN + i0 + t] = pss[t];
    }
}

// ---------------------------------------------------------------------------
// combine the 2 j-splits + bias. grid = 262144/256 = 1024 blocks.
// ---------------------------------------------------------------------------
__global__ __launch_bounds__(256) void combine_kernel(
    const float* __restrict__ pacc, const float* __restrict__ pm,
    const float* __restrict__ ps, const float* __restrict__ bias_param,
    float* __restrict__ out)
{
    int tid = blockIdx.x * 256 + threadIdx.x;
    int d = tid & 63;
    int row = tid >> 6;                 // bh*512 + n
    int bh = row >> 9, n = row & 511;
    int b = bh >> 2, hh = bh & 3;
    float m0 = pm[row], m1 = pm[4096 + row];
    float s0 = ps[row], s1 = ps[4096 + row];
    float M = fmaxf(m0, m1);
    float w0 = __expf(m0 - M), w1 = __expf(m1 - M);
    float inv = 1.f / fmaf(s0, w0, s1 * w1);
    float a0 = pacc[(size_t)row * 64 + d];
    float a1 = pacc[262144 + (size_t)row * 64 + d];
    out[((size_t)b * NN + n) * (HH * DD) + hh * DD + d] =
        fmaf(a0, w0, a1 * w1) * inv + bias_param[hh * DD + d];
}

extern "C" void kernel_launch(void* const* d_in, const int* in_sizes, int n_in,
                              void* d_out, int out_size, void* d_ws, size_t ws_size,
                              hipStream_t stream) {
    const float* x    = (const float*)d_in[0];
    const float* Wp   = (const float*)d_in[1];
    const float* bp   = (const float*)d_in[2];
    const float* Wc   = (const float*)d_in[3];
    const float* Wcb  = (const float*)d_in[4];
    const float* a    = (const float*)d_in[5];
    const float* bpar = (const float*)d_in[6];
    float* out = (float*)d_out;

    float* ws    = (float*)d_ws;
    float* h_ws   = ws;
    float* zi_ws  = ws + 262144;
    float* zj_ws  = ws + 524288;
    float* adi_ws = ws + 786432;
    float* adj_ws = ws + 790528;
    float* pacc   = ws + 794624;
    float* pm     = ws + 1318912;
    float* ps     = ws + 1327104;

    proj_kernel<<<dim3(512), dim3(256), 0, stream>>>(
        x, Wp, bp, Wc, Wcb, a, h_ws, zi_ws, zj_ws, adi_ws, adj_ws);
    attn_kernel<<<dim3(1024), dim3(256), 0, stream>>>(
        h_ws, zi_ws, zj_ws, a, adi_ws, adj_ws, pacc, pm, ps);
    combine_kernel<<<dim3(1024), dim3(256), 0, stream>>>(
        pacc, pm, ps, bpar, out);
}